// Round 2
// baseline (263.102 us; speedup 1.0000x reference)
//
#include <hip/hip_runtime.h>
#include <math.h>

// Problem constants (from reference)
#define Bn 8
#define Cn 32
#define Hn 120
#define Wn 160
#define HW (Hn*Wn)          // 19200
#define CHW (Cn*HW)         // 614400
#define OUTB (12 + CHW)     // 614412 floats per batch
#define DAMP_C 1e-4
#define OCC_THRES_C 0.1f

// ---------------------------------------------------------------------------
// init: copy input pose into ws pose buffer, zero accumulators
// ---------------------------------------------------------------------------
__global__ void init_kernel(const float* __restrict__ R_in,
                            const float* __restrict__ t_in,
                            float* __restrict__ pose,
                            float* __restrict__ accum) {
    int b = threadIdx.x;
    if (b < Bn) {
        for (int i = 0; i < 9; ++i) pose[b*12 + i] = R_in[b*9 + i];
        for (int i = 0; i < 3; ++i) pose[b*12 + 9 + i] = t_in[b*3 + i];
        for (int i = 0; i < 32; ++i) accum[b*32 + i] = 0.0f;
    }
}

// ---------------------------------------------------------------------------
// Sobel (edge-padded, cross-correlation like XLA conv) + normalize by mag
// One thread per element of (B*C, H, W)
// ---------------------------------------------------------------------------
__global__ __launch_bounds__(256) void sobel_kernel(const float* __restrict__ F1,
                                                    float* __restrict__ JFx,
                                                    float* __restrict__ JFy) {
    int idx = blockIdx.x * 256 + threadIdx.x;   // 0 .. B*CHW-1 (exact multiple)
    int p = idx % HW;
    int plane = idx / HW;
    int y = p / Wn, x = p % Wn;
    const float* Fp = F1 + (size_t)plane * HW;
    int ym = max(y-1, 0) * Wn, yc = y * Wn, yp = min(y+1, Hn-1) * Wn;
    int xm = max(x-1, 0), xp = min(x+1, Wn-1);
    float a00 = Fp[ym+xm], a01 = Fp[ym+x], a02 = Fp[ym+xp];
    float a10 = Fp[yc+xm],                 a12 = Fp[yc+xp];
    float a20 = Fp[yp+xm], a21 = Fp[yp+x], a22 = Fp[yp+xp];
    float dx = (a02 - a00) + 2.0f*(a12 - a10) + (a22 - a20);
    float dy = (a20 - a00) + 2.0f*(a21 - a01) + (a22 - a02);
    float mag = sqrtf(dx*dx + dy*dy + 1e-8f);
    JFx[idx] = dx / mag;
    JFy[idx] = dy / mag;
}

// ---------------------------------------------------------------------------
// Main per-pixel kernel: warp, residual, weights, JtJ (21) + rhs (6) partial
// accumulation. One thread per pixel, loops over 32 channels.
// Grid: Bn*HW/256 = 600 blocks, all pixels of one batch per 75 blocks.
// ---------------------------------------------------------------------------
template<bool LAST>
__global__ __launch_bounds__(256) void accum_kernel(
    const float* __restrict__ F0, const float* __restrict__ F1,
    const float* __restrict__ invD0, const float* __restrict__ invD1,
    const float* __restrict__ Kin,
    const float* __restrict__ JFx, const float* __restrict__ JFy,
    const float* __restrict__ pose, float* __restrict__ accum,
    float* __restrict__ out)
{
    __shared__ float sp[16];
    __shared__ float sred[4*27];
    const int BPB = HW / 256;                 // 75 blocks per batch
    int b = blockIdx.x / BPB;
    int p = (blockIdx.x % BPB) * 256 + threadIdx.x;
    if (threadIdx.x < 12) sp[threadIdx.x] = pose[b*12 + threadIdx.x];
    else if (threadIdx.x < 16) sp[threadIdx.x] = Kin[b*4 + threadIdx.x - 12];
    __syncthreads();
    float R0=sp[0],R1=sp[1],R2=sp[2],R3=sp[3],R4=sp[4],R5=sp[5],R6=sp[6],R7=sp[7],R8=sp[8];
    float t0=sp[9],t1=sp[10],t2=sp[11];
    float fx=sp[12],fy=sp[13],cx=sp[14],cy=sp[15];

    int y = p / Wn, x = p % Wn;
    float px = ((float)x - cx) / fx;
    float py = ((float)y - cy) / fy;
    float d = invD0[(size_t)b*HW + p];

    // _warp_inverse_depth: warped = R@[px,py,1] + t*d
    float X = R0*px + R1*py + R2 + t0*d;
    float Y = R3*px + R4*py + R5 + t1*d;
    float S = R6*px + R7*py + R8 + t2*d;
    float u = X / S * fx + cx;
    float v = Y / S * fy + cy;
    float iz = d / S;
    bool inview = (u > 0.0f) && (u < (float)(Wn-1)) && (v > 0.0f) && (v < (float)(Hn-1));

    // bilinear setup (clamped coords, as _warp_features)
    float uc = fminf(fmaxf(u, 0.0f), (float)(Wn-1));
    float vc = fminf(fmaxf(v, 0.0f), (float)(Hn-1));
    float x0f = floorf(uc), y0f = floorf(vc);
    float wx = uc - x0f, wy = vc - y0f;
    int x0 = (int)x0f, y0 = (int)y0f;
    int x1 = min(x0+1, Wn-1), y1 = min(y0+1, Hn-1);
    int i00 = y0*Wn + x0, i01 = y0*Wn + x1, i10 = y1*Wn + x0, i11 = y1*Wn + x1;
    float w00 = (1.0f-wx)*(1.0f-wy), w01 = wx*(1.0f-wy);
    float w10 = (1.0f-wx)*wy,        w11 = wx*wy;

    const float* iD1 = invD1 + (size_t)b*HW;
    float invD1w = iD1[i00]*w00 + iD1[i01]*w01 + iD1[i10]*w10 + iD1[i11]*w11;
    bool occ = !((iz > invD1w - OCC_THRES_C) && inview);

    // _jacobian_warping: warped = R@[px,py,d] + t
    float xj  = R0*px + R1*py + R2*d + t0;
    float yj  = R3*px + R4*py + R5*d + t1;
    float izj = R6*px + R7*py + R8*d + t2;
    float Jx[6], Jy[6];
    Jx[0] = -xj*yj*fx;        Jx[1] = (1.0f + xj*xj)*fx; Jx[2] = -yj*fx;
    Jx[3] = izj*fx;           Jx[4] = 0.0f;              Jx[5] = -izj*xj*fx;
    Jy[0] = -(1.0f + yj*yj)*fy; Jy[1] = xj*yj*fy;        Jy[2] = xj*fy;
    Jy[3] = 0.0f;             Jy[4] = izj*fy;            Jy[5] = -izj*yj*fy;

    // channel loop: reduce to 5 scalars
    const float* F0b = F0 + (size_t)b*CHW + p;
    const float* F1b = F1 + (size_t)b*CHW;
    const float* gxb = JFx + (size_t)b*CHW;
    const float* gyb = JFy + (size_t)b*CHW;
    float A2 = 0.0f, B2 = 0.0f, ABc = 0.0f, Sx = 0.0f, Sy = 0.0f;
    #pragma unroll 4
    for (int c = 0; c < Cn; ++c) {
        int base = c * HW;
        float f1w = F1b[base+i00]*w00 + F1b[base+i01]*w01 + F1b[base+i10]*w10 + F1b[base+i11]*w11;
        float gx  = gxb[base+i00]*w00 + gxb[base+i01]*w01 + gxb[base+i10]*w10 + gxb[base+i11]*w11;
        float gy  = gyb[base+i00]*w00 + gyb[base+i01]*w01 + gyb[base+i10]*w10 + gyb[base+i11]*w11;
        float r = occ ? 0.001f : (f1w - F0b[base]);
        float wt = 1.0f / (1.0f + r*r);
        if (LAST) out[(size_t)b*OUTB + 12 + base + p] = wt;
        A2 += gx*gx; B2 += gy*gy; ABc += gx*gy;
        float wr = wt * r;
        Sx += wr*gx; Sy += wr*gy;
    }

    // per-pixel 21 (sym JtJ) + 6 (rhs) partials
    float part[27];
    {
        int idx = 0;
        #pragma unroll
        for (int k = 0; k < 6; ++k)
            #pragma unroll
            for (int l = k; l < 6; ++l)
                part[idx++] = A2*Jx[k]*Jx[l] + ABc*(Jx[k]*Jy[l] + Jy[k]*Jx[l]) + B2*Jy[k]*Jy[l];
        #pragma unroll
        for (int k = 0; k < 6; ++k) part[21+k] = -(Sx*Jx[k] + Sy*Jy[k]);
    }

    // wave64 shuffle reduce, then cross-wave via LDS, then atomicAdd
    #pragma unroll
    for (int i = 0; i < 27; ++i) {
        float vsum = part[i];
        for (int off = 32; off > 0; off >>= 1) vsum += __shfl_down(vsum, off, 64);
        part[i] = vsum;
    }
    int lane = threadIdx.x & 63, wave = threadIdx.x >> 6;
    if (lane == 0)
        for (int i = 0; i < 27; ++i) sred[wave*27 + i] = part[i];
    __syncthreads();
    if (threadIdx.x < 27) {
        float s = sred[threadIdx.x] + sred[27+threadIdx.x] + sred[54+threadIdx.x] + sred[81+threadIdx.x];
        atomicAdd(&accum[b*32 + threadIdx.x], s);
    }
}

// ---------------------------------------------------------------------------
// 6x6 damped solve (fp64 GE + partial pivot), se3_exp, pose update.
// One thread per batch. Zeroes accum for the next iteration.
// ---------------------------------------------------------------------------
__global__ void solve_kernel(float* __restrict__ pose, float* __restrict__ accum,
                             float* __restrict__ out, int write_out) {
    int b = threadIdx.x;
    if (b >= Bn) return;
    double A[6][7];
    {
        float acc[27];
        for (int i = 0; i < 27; ++i) acc[i] = accum[b*32 + i];
        int idx = 0;
        for (int k = 0; k < 6; ++k)
            for (int l = k; l < 6; ++l) {
                double vv = (double)acc[idx++];
                A[k][l] = vv; A[l][k] = vv;
            }
        for (int k = 0; k < 6; ++k) { A[k][k] += DAMP_C; A[k][6] = (double)acc[21+k]; }
        for (int i = 0; i < 32; ++i) accum[b*32 + i] = 0.0f;   // ready for next iter
    }
    // Gaussian elimination with partial pivoting
    for (int col = 0; col < 6; ++col) {
        int piv = col;
        double mx = fabs(A[col][col]);
        for (int r = col+1; r < 6; ++r) { double a = fabs(A[r][col]); if (a > mx) { mx = a; piv = r; } }
        if (piv != col)
            for (int j = col; j < 7; ++j) { double tmp = A[col][j]; A[col][j] = A[piv][j]; A[piv][j] = tmp; }
        double inv = 1.0 / A[col][col];
        for (int r = col+1; r < 6; ++r) {
            double f = A[r][col] * inv;
            for (int j = col; j < 7; ++j) A[r][j] -= f * A[col][j];
        }
    }
    double dp[6];
    for (int col = 5; col >= 0; --col) {
        double s = A[col][6];
        for (int j = col+1; j < 6; ++j) s -= A[col][j] * dp[j];
        dp[col] = s / A[col][col];
    }
    // se3_exp
    double w0 = dp[0], w1 = dp[1], w2 = dp[2];
    double v0 = dp[3], v1 = dp[4], v2 = dp[5];
    double th2 = w0*w0 + w1*w1 + w2*w2;
    double th = sqrt(th2 + 1e-12);
    double a = sin(th) / th;
    double bb = (1.0 - cos(th)) / (th2 + 1e-12);
    double cc = (1.0 - a) / (th2 + 1e-12);
    double wxm[3][3] = {{0,-w2,w1},{w2,0,-w0},{-w1,w0,0}};
    double wx2[3][3];
    for (int i = 0; i < 3; ++i)
        for (int j = 0; j < 3; ++j) {
            double s = 0;
            for (int k = 0; k < 3; ++k) s += wxm[i][k]*wxm[k][j];
            wx2[i][j] = s;
        }
    double dR[3][3], V[3][3];
    for (int i = 0; i < 3; ++i)
        for (int j = 0; j < 3; ++j) {
            double I = (i == j) ? 1.0 : 0.0;
            dR[i][j] = I + a*wxm[i][j] + bb*wx2[i][j];
            V[i][j]  = I + bb*wxm[i][j] + cc*wx2[i][j];
        }
    double dt[3];
    for (int i = 0; i < 3; ++i) dt[i] = V[i][0]*v0 + V[i][1]*v1 + V[i][2]*v2;
    // pose update: t = dR@t + dt ; R = dR@R
    double Ro[3][3], to[3];
    for (int i = 0; i < 9; ++i) Ro[i/3][i%3] = (double)pose[b*12 + i];
    for (int i = 0; i < 3; ++i) to[i] = (double)pose[b*12 + 9 + i];
    double tn[3], Rn[3][3];
    for (int i = 0; i < 3; ++i)
        tn[i] = dR[i][0]*to[0] + dR[i][1]*to[1] + dR[i][2]*to[2] + dt[i];
    for (int i = 0; i < 3; ++i)
        for (int j = 0; j < 3; ++j)
            Rn[i][j] = dR[i][0]*Ro[0][j] + dR[i][1]*Ro[1][j] + dR[i][2]*Ro[2][j];
    for (int i = 0; i < 9; ++i) pose[b*12 + i] = (float)Rn[i/3][i%3];
    for (int i = 0; i < 3; ++i) pose[b*12 + 9 + i] = (float)tn[i];
    if (write_out) {
        for (int i = 0; i < 9; ++i) out[(size_t)b*OUTB + i] = (float)Rn[i/3][i%3];
        for (int i = 0; i < 3; ++i) out[(size_t)b*OUTB + 9 + i] = (float)tn[i];
    }
}

// ---------------------------------------------------------------------------
extern "C" void kernel_launch(void* const* d_in, const int* in_sizes, int n_in,
                              void* d_out, int out_size, void* d_ws, size_t ws_size,
                              hipStream_t stream) {
    const float* R_in  = (const float*)d_in[0];
    const float* t_in  = (const float*)d_in[1];
    const float* F0    = (const float*)d_in[2];
    const float* F1    = (const float*)d_in[3];
    const float* invD0 = (const float*)d_in[4];
    const float* invD1 = (const float*)d_in[5];
    const float* Kin   = (const float*)d_in[6];
    float* out = (float*)d_out;

    // workspace layout (floats): JFx[B*C*H*W] | JFy[B*C*H*W] | accum[B*32] | pose[B*12]
    float* ws = (float*)d_ws;
    float* JFx   = ws;
    float* JFy   = JFx + (size_t)Bn*CHW;
    float* accum = JFy + (size_t)Bn*CHW;
    float* pose  = accum + Bn*32;

    init_kernel<<<1, 64, 0, stream>>>(R_in, t_in, pose, accum);
    sobel_kernel<<<(Bn*CHW)/256, 256, 0, stream>>>(F1, JFx, JFy);

    for (int it = 0; it < 3; ++it) {
        bool last = (it == 2);
        if (last)
            accum_kernel<true><<<(Bn*HW)/256, 256, 0, stream>>>(
                F0, F1, invD0, invD1, Kin, JFx, JFy, pose, accum, out);
        else
            accum_kernel<false><<<(Bn*HW)/256, 256, 0, stream>>>(
                F0, F1, invD0, invD1, Kin, JFx, JFy, pose, accum, out);
        solve_kernel<<<1, 64, 0, stream>>>(pose, accum, out, last ? 1 : 0);
    }
}

// Round 3
// 250.234 us; speedup vs baseline: 1.0514x; 1.0514x over previous
//
#include <hip/hip_runtime.h>
#include <math.h>

// Problem constants (from reference)
#define Bn 8
#define Cn 32
#define Hn 120
#define Wn 160
#define HW (Hn*Wn)          // 19200
#define CHW (Cn*HW)         // 614400
#define OUTB (12 + CHW)     // 614412 floats per batch
#define DAMP_C 1e-4
#define OCC_THRES_C 0.1f

#define NCG 4               // channel groups per pixel-block
#define CPG (Cn/NCG)        // 8 channels per group
#define BPB (HW/256)        // 75 pixel-blocks per (batch, channel-group)

// ---------------------------------------------------------------------------
// init: copy input pose into ws pose buffer, zero accumulators
// ---------------------------------------------------------------------------
__global__ void init_kernel(const float* __restrict__ R_in,
                            const float* __restrict__ t_in,
                            float* __restrict__ pose,
                            float* __restrict__ accum) {
    int b = threadIdx.x;
    if (b < Bn) {
        for (int i = 0; i < 9; ++i) pose[b*12 + i] = R_in[b*9 + i];
        for (int i = 0; i < 3; ++i) pose[b*12 + 9 + i] = t_in[b*3 + i];
        for (int i = 0; i < 32; ++i) accum[b*32 + i] = 0.0f;
    }
}

// ---------------------------------------------------------------------------
// Sobel (edge-padded) + normalize; writes packed (gx,gy) float2
// ---------------------------------------------------------------------------
__global__ __launch_bounds__(256) void sobel_kernel(const float* __restrict__ F1,
                                                    float2* __restrict__ G) {
    int idx = blockIdx.x * 256 + threadIdx.x;   // 0 .. B*CHW-1 (exact multiple)
    int p = idx % HW;
    int plane = idx / HW;
    int y = p / Wn, x = p % Wn;
    const float* Fp = F1 + (size_t)plane * HW;
    int ym = max(y-1, 0) * Wn, yc = y * Wn, yp = min(y+1, Hn-1) * Wn;
    int xm = max(x-1, 0), xp = min(x+1, Wn-1);
    float a00 = Fp[ym+xm], a01 = Fp[ym+x], a02 = Fp[ym+xp];
    float a10 = Fp[yc+xm],                 a12 = Fp[yc+xp];
    float a20 = Fp[yp+xm], a21 = Fp[yp+x], a22 = Fp[yp+xp];
    float dx = (a02 - a00) + 2.0f*(a12 - a10) + (a22 - a20);
    float dy = (a20 - a00) + 2.0f*(a21 - a01) + (a22 - a02);
    float mag = sqrtf(dx*dx + dy*dy + 1e-8f);
    G[idx] = make_float2(dx / mag, dy / mag);
}

// ---------------------------------------------------------------------------
// Main kernel: one block = 256 pixels x 8 channels. Grid = Bn*NCG*BPB = 2400.
// Per-pixel setup recomputed per channel-group (VALU is cheap; latency isn't).
// 27 partials are linear in the 5 channel-sums -> per-group partials add up.
// ---------------------------------------------------------------------------
template<bool LAST>
__global__ __launch_bounds__(256) void accum_kernel(
    const float* __restrict__ F0, const float* __restrict__ F1,
    const float* __restrict__ invD0, const float* __restrict__ invD1,
    const float* __restrict__ Kin,
    const float2* __restrict__ G,
    const float* __restrict__ pose, float* __restrict__ accum,
    float* __restrict__ out)
{
    __shared__ float sp[16];
    __shared__ float sred[4*27];
    int blk = blockIdx.x;
    int pblk = blk % BPB;
    int cg   = (blk / BPB) % NCG;
    int b    = blk / (BPB * NCG);
    int p = pblk * 256 + threadIdx.x;
    if (threadIdx.x < 12) sp[threadIdx.x] = pose[b*12 + threadIdx.x];
    else if (threadIdx.x < 16) sp[threadIdx.x] = Kin[b*4 + threadIdx.x - 12];
    __syncthreads();
    float R0=sp[0],R1=sp[1],R2=sp[2],R3=sp[3],R4=sp[4],R5=sp[5],R6=sp[6],R7=sp[7],R8=sp[8];
    float t0=sp[9],t1=sp[10],t2=sp[11];
    float fx=sp[12],fy=sp[13],cx=sp[14],cy=sp[15];

    int y = p / Wn, x = p % Wn;
    float px = ((float)x - cx) / fx;
    float py = ((float)y - cy) / fy;
    float d = invD0[(size_t)b*HW + p];

    // _warp_inverse_depth: warped = R@[px,py,1] + t*d
    float X = R0*px + R1*py + R2 + t0*d;
    float Y = R3*px + R4*py + R5 + t1*d;
    float S = R6*px + R7*py + R8 + t2*d;
    float u = X / S * fx + cx;
    float v = Y / S * fy + cy;
    float iz = d / S;
    bool inview = (u > 0.0f) && (u < (float)(Wn-1)) && (v > 0.0f) && (v < (float)(Hn-1));

    // bilinear setup (clamped coords, as _warp_features)
    float uc = fminf(fmaxf(u, 0.0f), (float)(Wn-1));
    float vc = fminf(fmaxf(v, 0.0f), (float)(Hn-1));
    float x0f = floorf(uc), y0f = floorf(vc);
    float wx = uc - x0f, wy = vc - y0f;
    int x0 = (int)x0f, y0 = (int)y0f;
    int x1 = min(x0+1, Wn-1), y1 = min(y0+1, Hn-1);
    int i00 = y0*Wn + x0, i01 = y0*Wn + x1, i10 = y1*Wn + x0, i11 = y1*Wn + x1;
    float w00 = (1.0f-wx)*(1.0f-wy), w01 = wx*(1.0f-wy);
    float w10 = (1.0f-wx)*wy,        w11 = wx*wy;

    const float* iD1 = invD1 + (size_t)b*HW;
    float invD1w = iD1[i00]*w00 + iD1[i01]*w01 + iD1[i10]*w10 + iD1[i11]*w11;
    bool occ = !((iz > invD1w - OCC_THRES_C) && inview);

    // _jacobian_warping: warped = R@[px,py,d] + t
    float xj  = R0*px + R1*py + R2*d + t0;
    float yj  = R3*px + R4*py + R5*d + t1;
    float izj = R6*px + R7*py + R8*d + t2;
    float Jx[6], Jy[6];
    Jx[0] = -xj*yj*fx;        Jx[1] = (1.0f + xj*xj)*fx; Jx[2] = -yj*fx;
    Jx[3] = izj*fx;           Jx[4] = 0.0f;              Jx[5] = -izj*xj*fx;
    Jy[0] = -(1.0f + yj*yj)*fy; Jy[1] = xj*yj*fy;        Jy[2] = xj*fy;
    Jy[3] = 0.0f;             Jy[4] = izj*fy;            Jy[5] = -izj*yj*fy;

    // channel loop over this block's 8 channels: reduce to 5 scalars
    const float*  F0b = F0 + (size_t)b*CHW + p;
    const float*  F1b = F1 + (size_t)b*CHW;
    const float2* Gb  = G  + (size_t)b*CHW;
    int cbase0 = cg * CPG * HW;
    float A2 = 0.0f, B2 = 0.0f, ABc = 0.0f, Sx = 0.0f, Sy = 0.0f;
    #pragma unroll
    for (int cc = 0; cc < CPG; ++cc) {
        int base = cbase0 + cc * HW;
        float2 g00 = Gb[base+i00], g01 = Gb[base+i01];
        float2 g10 = Gb[base+i10], g11 = Gb[base+i11];
        float f1w = F1b[base+i00]*w00 + F1b[base+i01]*w01 + F1b[base+i10]*w10 + F1b[base+i11]*w11;
        float gx  = g00.x*w00 + g01.x*w01 + g10.x*w10 + g11.x*w11;
        float gy  = g00.y*w00 + g01.y*w01 + g10.y*w10 + g11.y*w11;
        float r = occ ? 0.001f : (f1w - F0b[base]);
        float wt = 1.0f / (1.0f + r*r);
        if (LAST) __builtin_nontemporal_store(wt, &out[(size_t)b*OUTB + 12 + base + p]);
        A2 += gx*gx; B2 += gy*gy; ABc += gx*gy;
        float wr = wt * r;
        Sx += wr*gx; Sy += wr*gy;
    }

    // per-pixel 21 (sym JtJ) + 6 (rhs) partials (linear in the 5 sums)
    float part[27];
    {
        int idx = 0;
        #pragma unroll
        for (int k = 0; k < 6; ++k)
            #pragma unroll
            for (int l = k; l < 6; ++l)
                part[idx++] = A2*Jx[k]*Jx[l] + ABc*(Jx[k]*Jy[l] + Jy[k]*Jx[l]) + B2*Jy[k]*Jy[l];
        #pragma unroll
        for (int k = 0; k < 6; ++k) part[21+k] = -(Sx*Jx[k] + Sy*Jy[k]);
    }

    // wave64 shuffle reduce, then cross-wave via LDS, then atomicAdd
    #pragma unroll
    for (int i = 0; i < 27; ++i) {
        float vsum = part[i];
        for (int off = 32; off > 0; off >>= 1) vsum += __shfl_down(vsum, off, 64);
        part[i] = vsum;
    }
    int lane = threadIdx.x & 63, wave = threadIdx.x >> 6;
    if (lane == 0)
        for (int i = 0; i < 27; ++i) sred[wave*27 + i] = part[i];
    __syncthreads();
    if (threadIdx.x < 27) {
        float s = sred[threadIdx.x] + sred[27+threadIdx.x] + sred[54+threadIdx.x] + sred[81+threadIdx.x];
        atomicAdd(&accum[b*32 + threadIdx.x], s);
    }
}

// ---------------------------------------------------------------------------
// 6x6 damped solve (fp64 GE + partial pivot), se3_exp (hw f32 sin/cos),
// pose update. One thread per batch. Zeroes accum for the next iteration.
// ---------------------------------------------------------------------------
__global__ void solve_kernel(float* __restrict__ pose, float* __restrict__ accum,
                             float* __restrict__ out, int write_out) {
    int b = threadIdx.x;
    if (b >= Bn) return;
    double A[6][7];
    {
        float acc[27];
        for (int i = 0; i < 27; ++i) acc[i] = accum[b*32 + i];
        int idx = 0;
        for (int k = 0; k < 6; ++k)
            for (int l = k; l < 6; ++l) {
                double vv = (double)acc[idx++];
                A[k][l] = vv; A[l][k] = vv;
            }
        for (int k = 0; k < 6; ++k) { A[k][k] += DAMP_C; A[k][6] = (double)acc[21+k]; }
        for (int i = 0; i < 32; ++i) accum[b*32 + i] = 0.0f;   // ready for next iter
    }
    // Gaussian elimination with partial pivoting
    for (int col = 0; col < 6; ++col) {
        int piv = col;
        double mx = fabs(A[col][col]);
        for (int r = col+1; r < 6; ++r) { double a = fabs(A[r][col]); if (a > mx) { mx = a; piv = r; } }
        if (piv != col)
            for (int j = col; j < 7; ++j) { double tmp = A[col][j]; A[col][j] = A[piv][j]; A[piv][j] = tmp; }
        double inv = 1.0 / A[col][col];
        for (int r = col+1; r < 6; ++r) {
            double f = A[r][col] * inv;
            for (int j = col; j < 7; ++j) A[r][j] -= f * A[col][j];
        }
    }
    double dp[6];
    for (int col = 5; col >= 0; --col) {
        double s = A[col][6];
        for (int j = col+1; j < 6; ++j) s -= A[col][j] * dp[j];
        dp[col] = s / A[col][col];
    }
    // se3_exp (transcendentals via f32 HW ops; matches reference f32 math)
    double w0 = dp[0], w1 = dp[1], w2 = dp[2];
    double v0 = dp[3], v1 = dp[4], v2 = dp[5];
    double th2 = w0*w0 + w1*w1 + w2*w2;
    double th = sqrt(th2 + 1e-12);
    float thf = (float)th;
    double sth = (double)sinf(thf);
    double cth = (double)cosf(thf);
    double a = sth / th;
    double bb = (1.0 - cth) / (th2 + 1e-12);
    double cc = (1.0 - a) / (th2 + 1e-12);
    double wxm[3][3] = {{0,-w2,w1},{w2,0,-w0},{-w1,w0,0}};
    double wx2[3][3];
    for (int i = 0; i < 3; ++i)
        for (int j = 0; j < 3; ++j) {
            double s = 0;
            for (int k = 0; k < 3; ++k) s += wxm[i][k]*wxm[k][j];
            wx2[i][j] = s;
        }
    double dR[3][3], V[3][3];
    for (int i = 0; i < 3; ++i)
        for (int j = 0; j < 3; ++j) {
            double I = (i == j) ? 1.0 : 0.0;
            dR[i][j] = I + a*wxm[i][j] + bb*wx2[i][j];
            V[i][j]  = I + bb*wxm[i][j] + cc*wx2[i][j];
        }
    double dt[3];
    for (int i = 0; i < 3; ++i) dt[i] = V[i][0]*v0 + V[i][1]*v1 + V[i][2]*v2;
    // pose update: t = dR@t + dt ; R = dR@R
    double Ro[3][3], to[3];
    for (int i = 0; i < 9; ++i) Ro[i/3][i%3] = (double)pose[b*12 + i];
    for (int i = 0; i < 3; ++i) to[i] = (double)pose[b*12 + 9 + i];
    double tn[3], Rn[3][3];
    for (int i = 0; i < 3; ++i)
        tn[i] = dR[i][0]*to[0] + dR[i][1]*to[1] + dR[i][2]*to[2] + dt[i];
    for (int i = 0; i < 3; ++i)
        for (int j = 0; j < 3; ++j)
            Rn[i][j] = dR[i][0]*Ro[0][j] + dR[i][1]*Ro[1][j] + dR[i][2]*Ro[2][j];
    for (int i = 0; i < 9; ++i) pose[b*12 + i] = (float)Rn[i/3][i%3];
    for (int i = 0; i < 3; ++i) pose[b*12 + 9 + i] = (float)tn[i];
    if (write_out) {
        for (int i = 0; i < 9; ++i) out[(size_t)b*OUTB + i] = (float)Rn[i/3][i%3];
        for (int i = 0; i < 3; ++i) out[(size_t)b*OUTB + 9 + i] = (float)tn[i];
    }
}

// ---------------------------------------------------------------------------
extern "C" void kernel_launch(void* const* d_in, const int* in_sizes, int n_in,
                              void* d_out, int out_size, void* d_ws, size_t ws_size,
                              hipStream_t stream) {
    const float* R_in  = (const float*)d_in[0];
    const float* t_in  = (const float*)d_in[1];
    const float* F0    = (const float*)d_in[2];
    const float* F1    = (const float*)d_in[3];
    const float* invD0 = (const float*)d_in[4];
    const float* invD1 = (const float*)d_in[5];
    const float* Kin   = (const float*)d_in[6];
    float* out = (float*)d_out;

    // workspace layout: G[B*C*H*W] float2 | accum[B*32] f32 | pose[B*12] f32
    float2* G    = (float2*)d_ws;
    float* accum = (float*)(G + (size_t)Bn*CHW);
    float* pose  = accum + Bn*32;

    init_kernel<<<1, 64, 0, stream>>>(R_in, t_in, pose, accum);
    sobel_kernel<<<(Bn*CHW)/256, 256, 0, stream>>>(F1, G);

    for (int it = 0; it < 3; ++it) {
        bool last = (it == 2);
        if (last)
            accum_kernel<true><<<Bn*NCG*BPB, 256, 0, stream>>>(
                F0, F1, invD0, invD1, Kin, G, pose, accum, out);
        else
            accum_kernel<false><<<Bn*NCG*BPB, 256, 0, stream>>>(
                F0, F1, invD0, invD1, Kin, G, pose, accum, out);
        solve_kernel<<<1, 64, 0, stream>>>(pose, accum, out, last ? 1 : 0);
    }
}

// Round 4
// 228.250 us; speedup vs baseline: 1.1527x; 1.0963x over previous
//
#include <hip/hip_runtime.h>
#include <hip/hip_fp16.h>
#include <math.h>

// Problem constants (from reference)
#define Bn 8
#define Cn 32
#define Hn 120
#define Wn 160
#define HW (Hn*Wn)          // 19200
#define CHW (Cn*HW)         // 614400
#define OUTB (12 + CHW)     // 614412 floats per batch
#define DAMP_C 1e-4
#define OCC_THRES_C 0.1f

#define NCG 4               // channel groups per pixel-block
#define CPG (Cn/NCG)        // 8 channels per group
#define BPB (HW/256)        // 75 pixel-blocks per (batch, channel-group)

// ---------------------------------------------------------------------------
// init: copy input pose into ws pose buffer, zero accumulators
// ---------------------------------------------------------------------------
__global__ void init_kernel(const float* __restrict__ R_in,
                            const float* __restrict__ t_in,
                            float* __restrict__ pose,
                            float* __restrict__ accum) {
    int b = threadIdx.x;
    if (b < Bn) {
        for (int i = 0; i < 9; ++i) pose[b*12 + i] = R_in[b*9 + i];
        for (int i = 0; i < 3; ++i) pose[b*12 + 9 + i] = t_in[b*3 + i];
        for (int i = 0; i < 32; ++i) accum[b*32 + i] = 0.0f;
    }
}

// ---------------------------------------------------------------------------
// prep: Sobel (edge-padded) + normalize -> half2 G; also F1->half, F0->half.
// One thread per element of (B*C, H, W).
// ---------------------------------------------------------------------------
__global__ __launch_bounds__(256) void prep_kernel(const float* __restrict__ F1,
                                                   const float* __restrict__ F0,
                                                   __half2* __restrict__ Gh,
                                                   __half* __restrict__ F1h,
                                                   __half* __restrict__ F0h) {
    int idx = blockIdx.x * 256 + threadIdx.x;   // 0 .. B*CHW-1 (exact multiple)
    int p = idx % HW;
    int plane = idx / HW;
    int y = p / Wn, x = p % Wn;
    const float* Fp = F1 + (size_t)plane * HW;
    int ym = max(y-1, 0) * Wn, yc = y * Wn, yp = min(y+1, Hn-1) * Wn;
    int xm = max(x-1, 0), xp = min(x+1, Wn-1);
    float a00 = Fp[ym+xm], a01 = Fp[ym+x], a02 = Fp[ym+xp];
    float a10 = Fp[yc+xm], a11 = Fp[yc+x], a12 = Fp[yc+xp];
    float a20 = Fp[yp+xm], a21 = Fp[yp+x], a22 = Fp[yp+xp];
    float dx = (a02 - a00) + 2.0f*(a12 - a10) + (a22 - a20);
    float dy = (a20 - a00) + 2.0f*(a21 - a01) + (a22 - a02);
    float mag = sqrtf(dx*dx + dy*dy + 1e-8f);
    Gh[idx]  = __floats2half2_rn(dx / mag, dy / mag);
    F1h[idx] = __float2half(a11);
    F0h[idx] = __float2half(F0[idx]);
}

// ---------------------------------------------------------------------------
// Main kernel: one block = 256 pixels x 8 channels. Grid = Bn*NCG*BPB = 2400.
// Gathers are fp16; loads batched 4 channels at a time into register arrays
// to maximize memory-level parallelism (latency-bound regime).
// ---------------------------------------------------------------------------
template<bool LAST>
__global__ __launch_bounds__(256) void accum_kernel(
    const float* __restrict__ invD0, const float* __restrict__ invD1,
    const float* __restrict__ Kin,
    const __half* __restrict__ F1h, const __half* __restrict__ F0h,
    const __half2* __restrict__ Gh,
    const float* __restrict__ pose, float* __restrict__ accum,
    float* __restrict__ out)
{
    __shared__ float sp[16];
    __shared__ float sred[4*27];
    int blk = blockIdx.x;
    int pblk = blk % BPB;
    int cg   = (blk / BPB) % NCG;
    int b    = blk / (BPB * NCG);
    int p = pblk * 256 + threadIdx.x;
    if (threadIdx.x < 12) sp[threadIdx.x] = pose[b*12 + threadIdx.x];
    else if (threadIdx.x < 16) sp[threadIdx.x] = Kin[b*4 + threadIdx.x - 12];
    __syncthreads();
    float R0=sp[0],R1=sp[1],R2=sp[2],R3=sp[3],R4=sp[4],R5=sp[5],R6=sp[6],R7=sp[7],R8=sp[8];
    float t0=sp[9],t1=sp[10],t2=sp[11];
    float fx=sp[12],fy=sp[13],cx=sp[14],cy=sp[15];

    int y = p / Wn, x = p % Wn;
    float px = ((float)x - cx) / fx;
    float py = ((float)y - cy) / fy;
    float d = invD0[(size_t)b*HW + p];

    // _warp_inverse_depth: warped = R@[px,py,1] + t*d   (all f32 — booleans
    // bit-identical to the f32 reference path)
    float X = R0*px + R1*py + R2 + t0*d;
    float Y = R3*px + R4*py + R5 + t1*d;
    float S = R6*px + R7*py + R8 + t2*d;
    float u = X / S * fx + cx;
    float v = Y / S * fy + cy;
    float iz = d / S;
    bool inview = (u > 0.0f) && (u < (float)(Wn-1)) && (v > 0.0f) && (v < (float)(Hn-1));

    // bilinear setup (clamped coords, as _warp_features)
    float uc = fminf(fmaxf(u, 0.0f), (float)(Wn-1));
    float vc = fminf(fmaxf(v, 0.0f), (float)(Hn-1));
    float x0f = floorf(uc), y0f = floorf(vc);
    float wx = uc - x0f, wy = vc - y0f;
    int x0 = (int)x0f, y0 = (int)y0f;
    int x1 = min(x0+1, Wn-1), y1 = min(y0+1, Hn-1);
    int i00 = y0*Wn + x0, i01 = y0*Wn + x1, i10 = y1*Wn + x0, i11 = y1*Wn + x1;
    float w00 = (1.0f-wx)*(1.0f-wy), w01 = wx*(1.0f-wy);
    float w10 = (1.0f-wx)*wy,        w11 = wx*wy;

    const float* iD1 = invD1 + (size_t)b*HW;
    float invD1w = iD1[i00]*w00 + iD1[i01]*w01 + iD1[i10]*w10 + iD1[i11]*w11;
    bool occ = !((iz > invD1w - OCC_THRES_C) && inview);

    // _jacobian_warping: warped = R@[px,py,d] + t
    float xj  = R0*px + R1*py + R2*d + t0;
    float yj  = R3*px + R4*py + R5*d + t1;
    float izj = R6*px + R7*py + R8*d + t2;
    float Jx[6], Jy[6];
    Jx[0] = -xj*yj*fx;        Jx[1] = (1.0f + xj*xj)*fx; Jx[2] = -yj*fx;
    Jx[3] = izj*fx;           Jx[4] = 0.0f;              Jx[5] = -izj*xj*fx;
    Jy[0] = -(1.0f + yj*yj)*fy; Jy[1] = xj*yj*fy;        Jy[2] = xj*fy;
    Jy[3] = 0.0f;             Jy[4] = izj*fy;            Jy[5] = -izj*yj*fy;

    // channel loop over this block's 8 channels, in two 4-channel batches.
    // Each batch: (load phase -> 36 loads in flight) then (convert+FMA phase).
    const __half*  F1b = F1h + (size_t)b*CHW;
    const __half*  F0b = F0h + (size_t)b*CHW + p;
    const __half2* Gb  = Gh  + (size_t)b*CHW;
    int cbase0 = cg * CPG * HW;
    float A2 = 0.0f, B2 = 0.0f, ABc = 0.0f, Sx = 0.0f, Sy = 0.0f;
    #pragma unroll
    for (int hb = 0; hb < 2; ++hb) {
        __half  l00[4], l01[4], l10[4], l11[4], lf0[4];
        __half2 g00[4], g01[4], g10[4], g11[4];
        #pragma unroll
        for (int cc = 0; cc < 4; ++cc) {
            int base = cbase0 + (hb*4 + cc) * HW;
            l00[cc] = F1b[base+i00]; l01[cc] = F1b[base+i01];
            l10[cc] = F1b[base+i10]; l11[cc] = F1b[base+i11];
            g00[cc] = Gb[base+i00];  g01[cc] = Gb[base+i01];
            g10[cc] = Gb[base+i10];  g11[cc] = Gb[base+i11];
            lf0[cc] = F0b[base];
        }
        #pragma unroll
        for (int cc = 0; cc < 4; ++cc) {
            int base = cbase0 + (hb*4 + cc) * HW;
            float f1w = __half2float(l00[cc])*w00 + __half2float(l01[cc])*w01
                      + __half2float(l10[cc])*w10 + __half2float(l11[cc])*w11;
            float2 G00 = __half22float2(g00[cc]), G01 = __half22float2(g01[cc]);
            float2 G10 = __half22float2(g10[cc]), G11 = __half22float2(g11[cc]);
            float gx = G00.x*w00 + G01.x*w01 + G10.x*w10 + G11.x*w11;
            float gy = G00.y*w00 + G01.y*w01 + G10.y*w10 + G11.y*w11;
            float r = occ ? 0.001f : (f1w - __half2float(lf0[cc]));
            float wt = 1.0f / (1.0f + r*r);
            if (LAST) __builtin_nontemporal_store(wt, &out[(size_t)b*OUTB + 12 + base + p]);
            A2 += gx*gx; B2 += gy*gy; ABc += gx*gy;
            float wr = wt * r;
            Sx += wr*gx; Sy += wr*gy;
        }
    }

    // per-pixel 21 (sym JtJ) + 6 (rhs) partials (linear in the 5 sums)
    float part[27];
    {
        int idx = 0;
        #pragma unroll
        for (int k = 0; k < 6; ++k)
            #pragma unroll
            for (int l = k; l < 6; ++l)
                part[idx++] = A2*Jx[k]*Jx[l] + ABc*(Jx[k]*Jy[l] + Jy[k]*Jx[l]) + B2*Jy[k]*Jy[l];
        #pragma unroll
        for (int k = 0; k < 6; ++k) part[21+k] = -(Sx*Jx[k] + Sy*Jy[k]);
    }

    // wave64 shuffle reduce, then cross-wave via LDS, then atomicAdd
    #pragma unroll
    for (int i = 0; i < 27; ++i) {
        float vsum = part[i];
        for (int off = 32; off > 0; off >>= 1) vsum += __shfl_down(vsum, off, 64);
        part[i] = vsum;
    }
    int lane = threadIdx.x & 63, wave = threadIdx.x >> 6;
    if (lane == 0)
        for (int i = 0; i < 27; ++i) sred[wave*27 + i] = part[i];
    __syncthreads();
    if (threadIdx.x < 27) {
        float s = sred[threadIdx.x] + sred[27+threadIdx.x] + sred[54+threadIdx.x] + sred[81+threadIdx.x];
        atomicAdd(&accum[b*32 + threadIdx.x], s);
    }
}

// ---------------------------------------------------------------------------
// 6x6 damped solve (fp64 GE + partial pivot), se3_exp (hw f32 sin/cos),
// pose update. One thread per batch. Zeroes accum for the next iteration.
// ---------------------------------------------------------------------------
__global__ void solve_kernel(float* __restrict__ pose, float* __restrict__ accum,
                             float* __restrict__ out, int write_out) {
    int b = threadIdx.x;
    if (b >= Bn) return;
    double A[6][7];
    {
        float acc[27];
        for (int i = 0; i < 27; ++i) acc[i] = accum[b*32 + i];
        int idx = 0;
        for (int k = 0; k < 6; ++k)
            for (int l = k; l < 6; ++l) {
                double vv = (double)acc[idx++];
                A[k][l] = vv; A[l][k] = vv;
            }
        for (int k = 0; k < 6; ++k) { A[k][k] += DAMP_C; A[k][6] = (double)acc[21+k]; }
        for (int i = 0; i < 32; ++i) accum[b*32 + i] = 0.0f;   // ready for next iter
    }
    // Gaussian elimination with partial pivoting
    for (int col = 0; col < 6; ++col) {
        int piv = col;
        double mx = fabs(A[col][col]);
        for (int r = col+1; r < 6; ++r) { double a = fabs(A[r][col]); if (a > mx) { mx = a; piv = r; } }
        if (piv != col)
            for (int j = col; j < 7; ++j) { double tmp = A[col][j]; A[col][j] = A[piv][j]; A[piv][j] = tmp; }
        double inv = 1.0 / A[col][col];
        for (int r = col+1; r < 6; ++r) {
            double f = A[r][col] * inv;
            for (int j = col; j < 7; ++j) A[r][j] -= f * A[col][j];
        }
    }
    double dp[6];
    for (int col = 5; col >= 0; --col) {
        double s = A[col][6];
        for (int j = col+1; j < 6; ++j) s -= A[col][j] * dp[j];
        dp[col] = s / A[col][col];
    }
    // se3_exp (transcendentals via f32 HW ops; matches reference f32 math)
    double w0 = dp[0], w1 = dp[1], w2 = dp[2];
    double v0 = dp[3], v1 = dp[4], v2 = dp[5];
    double th2 = w0*w0 + w1*w1 + w2*w2;
    double th = sqrt(th2 + 1e-12);
    float thf = (float)th;
    double sth = (double)sinf(thf);
    double cth = (double)cosf(thf);
    double a = sth / th;
    double bb = (1.0 - cth) / (th2 + 1e-12);
    double cc = (1.0 - a) / (th2 + 1e-12);
    double wxm[3][3] = {{0,-w2,w1},{w2,0,-w0},{-w1,w0,0}};
    double wx2[3][3];
    for (int i = 0; i < 3; ++i)
        for (int j = 0; j < 3; ++j) {
            double s = 0;
            for (int k = 0; k < 3; ++k) s += wxm[i][k]*wxm[k][j];
            wx2[i][j] = s;
        }
    double dR[3][3], V[3][3];
    for (int i = 0; i < 3; ++i)
        for (int j = 0; j < 3; ++j) {
            double I = (i == j) ? 1.0 : 0.0;
            dR[i][j] = I + a*wxm[i][j] + bb*wx2[i][j];
            V[i][j]  = I + bb*wxm[i][j] + cc*wx2[i][j];
        }
    double dt[3];
    for (int i = 0; i < 3; ++i) dt[i] = V[i][0]*v0 + V[i][1]*v1 + V[i][2]*v2;
    // pose update: t = dR@t + dt ; R = dR@R
    double Ro[3][3], to[3];
    for (int i = 0; i < 9; ++i) Ro[i/3][i%3] = (double)pose[b*12 + i];
    for (int i = 0; i < 3; ++i) to[i] = (double)pose[b*12 + 9 + i];
    double tn[3], Rn[3][3];
    for (int i = 0; i < 3; ++i)
        tn[i] = dR[i][0]*to[0] + dR[i][1]*to[1] + dR[i][2]*to[2] + dt[i];
    for (int i = 0; i < 3; ++i)
        for (int j = 0; j < 3; ++j)
            Rn[i][j] = dR[i][0]*Ro[0][j] + dR[i][1]*Ro[1][j] + dR[i][2]*Ro[2][j];
    for (int i = 0; i < 9; ++i) pose[b*12 + i] = (float)Rn[i/3][i%3];
    for (int i = 0; i < 3; ++i) pose[b*12 + 9 + i] = (float)tn[i];
    if (write_out) {
        for (int i = 0; i < 9; ++i) out[(size_t)b*OUTB + i] = (float)Rn[i/3][i%3];
        for (int i = 0; i < 3; ++i) out[(size_t)b*OUTB + 9 + i] = (float)tn[i];
    }
}

// ---------------------------------------------------------------------------
extern "C" void kernel_launch(void* const* d_in, const int* in_sizes, int n_in,
                              void* d_out, int out_size, void* d_ws, size_t ws_size,
                              hipStream_t stream) {
    const float* R_in  = (const float*)d_in[0];
    const float* t_in  = (const float*)d_in[1];
    const float* F0    = (const float*)d_in[2];
    const float* F1    = (const float*)d_in[3];
    const float* invD0 = (const float*)d_in[4];
    const float* invD1 = (const float*)d_in[5];
    const float* Kin   = (const float*)d_in[6];
    float* out = (float*)d_out;

    // ws layout: Gh half2[B*CHW] | F1h half[B*CHW] | F0h half[B*CHW]
    //            | accum f32[B*32] | pose f32[B*12]
    __half2* Gh  = (__half2*)d_ws;
    __half*  F1h = (__half*)(Gh + (size_t)Bn*CHW);
    __half*  F0h = F1h + (size_t)Bn*CHW;
    float* accum = (float*)(F0h + (size_t)Bn*CHW);
    float* pose  = accum + Bn*32;

    init_kernel<<<1, 64, 0, stream>>>(R_in, t_in, pose, accum);
    prep_kernel<<<(Bn*CHW)/256, 256, 0, stream>>>(F1, F0, Gh, F1h, F0h);

    for (int it = 0; it < 3; ++it) {
        bool last = (it == 2);
        if (last)
            accum_kernel<true><<<Bn*NCG*BPB, 256, 0, stream>>>(
                invD0, invD1, Kin, F1h, F0h, Gh, pose, accum, out);
        else
            accum_kernel<false><<<Bn*NCG*BPB, 256, 0, stream>>>(
                invD0, invD1, Kin, F1h, F0h, Gh, pose, accum, out);
        solve_kernel<<<1, 64, 0, stream>>>(pose, accum, out, last ? 1 : 0);
    }
}